// Round 7
// baseline (576.637 us; speedup 1.0000x reference)
//
#include <hip/hip_runtime.h>
#include <hip/hip_fp16.h>

constexpr int NB   = 2048;
constexpr int EMB  = 16;
constexpr int NV   = 89;
constexpr int NN   = NB * NV;      // 182272 nodes (= 712 * 256)
constexpr int NEdg = 16 * NN;      // 2916352 edges (= 712 * 4096)
constexpr int H0   = 32;
constexpr int H1   = 64;
constexpr int NOUT = 3;
constexpr int NBKT = NN / 256;     // 712 buckets of 256 nodes
constexpr int EPB  = NEdg / NBKT;  // 4096 edges per hist/scatter block
constexpr float BN_EPS = 1e-5f;

struct __align__(8) h4 { __half2 a, b; };   // 8B packed 4x fp16

// ---- pass A: per-block LDS histogram -> blkOff[block][bucket] ----
__global__ __launch_bounds__(256) void k_hist(const int* __restrict__ dst,
                                              int* __restrict__ blkOff) {
  __shared__ int h[NBKT];
  int t = threadIdx.x, b = blockIdx.x;
  for (int i = t; i < NBKT; i += 256) h[i] = 0;
  __syncthreads();
  int base = b * EPB;
  #pragma unroll
  for (int k = 0; k < EPB / 256; ++k)
    atomicAdd(&h[dst[base + t + k * 256] >> 8], 1);
  __syncthreads();
  for (int i = t; i < NBKT; i += 256) blkOff[(size_t)b * NBKT + i] = h[i];
}

// ---- per-bucket column scan over blocks; bktCnt = totals ----
__global__ __launch_bounds__(256) void k_colscan(int* __restrict__ blkOff,
                                                 int* __restrict__ bktCnt) {
  __shared__ int s[256];
  int t = threadIdx.x, k = blockIdx.x;
  int b0 = t * 3;
  int v0 = (b0     < NBKT) ? blkOff[(size_t)(b0    ) * NBKT + k] : 0;
  int v1 = (b0 + 1 < NBKT) ? blkOff[(size_t)(b0 + 1) * NBKT + k] : 0;
  int v2 = (b0 + 2 < NBKT) ? blkOff[(size_t)(b0 + 2) * NBKT + k] : 0;
  int ts = v0 + v1 + v2;
  s[t] = ts;
  __syncthreads();
  for (int off = 1; off < 256; off <<= 1) {
    int a = (t >= off) ? s[t - off] : 0;
    __syncthreads();
    s[t] += a;
    __syncthreads();
  }
  int pre = s[t] - ts;
  if (b0     < NBKT) blkOff[(size_t)(b0    ) * NBKT + k] = pre;
  if (b0 + 1 < NBKT) blkOff[(size_t)(b0 + 1) * NBKT + k] = pre + v0;
  if (b0 + 2 < NBKT) blkOff[(size_t)(b0 + 2) * NBKT + k] = pre + v0 + v1;
  if (t == 255) bktCnt[k] = s[255];
}

// ---- bucket scan: bktCnt -> bktPtr (exclusive) ----
__global__ void k_scanB(const int* __restrict__ bktCnt, int* __restrict__ bktPtr) {
  __shared__ int s[1024];
  int t = threadIdx.x;
  int v = (t < NBKT) ? bktCnt[t] : 0;
  s[t] = v;
  __syncthreads();
  for (int off = 1; off < 1024; off <<= 1) {
    int a = (t >= off) ? s[t - off] : 0;
    __syncthreads();
    s[t] += a;
    __syncthreads();
  }
  if (t < NBKT) bktPtr[t] = s[t] - v;
}

// ---- pass B: place records bucket-grouped (LDS cursors only) ----
__global__ __launch_bounds__(256) void k_scat(const int* __restrict__ src,
                                              const int* __restrict__ dst,
                                              const float* __restrict__ ew,
                                              const int* __restrict__ blkOff,
                                              const int* __restrict__ bktPtr,
                                              uint2* __restrict__ recs) {
  __shared__ int cur[NBKT];
  int t = threadIdx.x, b = blockIdx.x;
  for (int i = t; i < NBKT; i += 256)
    cur[i] = bktPtr[i] + blkOff[(size_t)b * NBKT + i];
  __syncthreads();
  int base = b * EPB;
  #pragma unroll
  for (int k = 0; k < EPB / 256; ++k) {
    int e = base + t + k * 256;
    int d = dst[e];
    int p = atomicAdd(&cur[d >> 8], 1);
    recs[p] = make_uint2(((unsigned)src[e] << 8) | (unsigned)(d & 255),
                         __float_as_uint(ew[e]));
  }
}

// ---- pass C: in-bucket sort by node -> recs2 + rowptr + fused degree->dinv ----
__global__ __launch_bounds__(256) void k_sort2(
    const int* __restrict__ bktPtr, const int* __restrict__ bktCnt,
    const uint2* __restrict__ recs,
    uint2* __restrict__ recs2, int* __restrict__ rowptr,
    float* __restrict__ dinv) {
  __shared__ int sc[256];
  __shared__ int cur[256];
  __shared__ float dg[256];
  int t = threadIdx.x, k = blockIdx.x;
  sc[t] = 0;
  dg[t] = 0.f;
  __syncthreads();
  int beg = bktPtr[k], cnt = bktCnt[k];
  for (int i = t; i < cnt; i += 256) {
    uint2 r = recs[beg + i];
    atomicAdd(&sc[r.x & 255], 1);
    atomicAdd(&dg[r.x & 255], __uint_as_float(r.y));
  }
  __syncthreads();
  dinv[k * 256 + t] = rsqrtf(dg[t] + 1.0f);
  int v = sc[t];
  __syncthreads();
  sc[t] = v;
  __syncthreads();
  for (int off = 1; off < 256; off <<= 1) {
    int a = (t >= off) ? sc[t - off] : 0;
    __syncthreads();
    sc[t] += a;
    __syncthreads();
  }
  int excl = beg + sc[t] - v;
  cur[t] = excl;
  rowptr[k * 256 + t] = excl;
  if (k == NBKT - 1 && t == 0) rowptr[NN] = NEdg;
  __syncthreads();
  for (int i = t; i < cnt; i += 256) {
    uint2 r = recs[beg + i];
    int p = atomicAdd(&cur[r.x & 255], 1);
    recs2[p] = r;                      // raw {src<<8|row, w}
  }
}

// ---- layer-1 edge pass (round R handles ge dims R*8..R*8+7) ----
template<int R>
__device__ __forceinline__ void edge_pass(
    int n, int lane, int j, int q,
    const int* __restrict__ rowptr, const uint2* __restrict__ recs,
    const float* __restrict__ dinv, const float* __restrict__ ge,
    const h4* __restrict__ Wh, const h4* __restrict__ bxh,
    float dd, float4& acc) {
  int beg = rowptr[n], end = rowptr[n + 1];
  int cnt = end - beg, tot = cnt + 1;          // + virtual self-loop
  for (int base = 0; base < tot; base += 64) {
    int idx = base + lane;
    unsigned pv = 0u; float f = 0.f;
    if (idx < cnt) {
      uint2 r = recs[beg + idx];
      unsigned s = r.x >> 8;
      unsigned g = s / 89u;
      pv = (g << 7) | (s - g * 89u);
      f = dinv[s] * __uint_as_float(r.y);
    } else if (idx == cnt) {
      unsigned s = (unsigned)n;
      unsigned g = s / 89u;
      pv = (g << 7) | (s - g * 89u);
      f = dd;
    }
    // premultiply this edge's ge slice by f (in prefetch lane)
    float fu0, fu1, fu2, fu3, fu4, fu5, fu6, fu7;
    {
      unsigned g = pv >> 7;
      const float4* gp = (const float4*)(ge + g * 16u + R * 8);
      float4 u0 = gp[0], u1 = gp[1];
      fu0 = f * u0.x; fu1 = f * u0.y; fu2 = f * u0.z; fu3 = f * u0.w;
      fu4 = f * u1.x; fu5 = f * u1.y; fu6 = f * u1.z; fu7 = f * u1.w;
    }
    int c = tot - base; c = c < 64 ? c : 64;
    for (int b0 = 0; b0 < c; b0 += 8) {
      int jj = b0 + j;
      unsigned pvj = (unsigned)__shfl((int)pv, jj);
      float s0 = __shfl(fu0, jj), s1 = __shfl(fu1, jj),
            s2 = __shfl(fu2, jj), s3 = __shfl(fu3, jj),
            s4 = __shfl(fu4, jj), s5 = __shfl(fu5, jj),
            s6 = __shfl(fu6, jj), s7 = __shfl(fu7, jj);
      float fj = __shfl(f, jj);
      if (jj < c) {
        unsigned v = pvj & 127u;
        const h4* wp = Wh + (v * 65u + q);
        if (R == 0) {                         // bias once (round A)
          h4 bb = bxh[v * 9u + q];
          float2 bl = __half22float2(bb.a), bh = __half22float2(bb.b);
          acc.x += fj * bl.x; acc.y += fj * bl.y;
          acc.z += fj * bh.x; acc.w += fj * bh.y;
        }
        #pragma unroll
        for (int kk = 0; kk < 8; ++kk) {
          h4 wv = wp[kk * 8];
          float2 w0 = __half22float2(wv.a), w1 = __half22float2(wv.b);
          float fk = (kk==0)?s0:(kk==1)?s1:(kk==2)?s2:(kk==3)?s3:
                     (kk==4)?s4:(kk==5)?s5:(kk==6)?s6:s7;
          acc.x += fk * w0.x; acc.y += fk * w0.y;
          acc.z += fk * w1.x; acc.w += fk * w1.y;
        }
      }
    }
  }
}

// ---- layer 1: edges via (ge @ Wexp) on the fly + W1/BN/ReLU/W2 -> z[N,4] ----
__global__ __launch_bounds__(256) void k_e1(
    const int* __restrict__ rowptr, const uint2* __restrict__ recs,
    const float* __restrict__ dinv, const float* __restrict__ ge,
    const float* __restrict__ Wexp, const float* __restrict__ bexp,
    const float* __restrict__ W1, const float* __restrict__ b1,
    const float* __restrict__ W2,
    const float* __restrict__ gamma, const float* __restrict__ beta,
    const float* __restrict__ mean, const float* __restrict__ var,
    float* __restrict__ z) {
  __shared__ __align__(16) unsigned char smem[52688];
  h4* Wh  = (h4*)smem;                     // 89*65 chunks = 46280 B
  h4* bxh = (h4*)(smem + 46280);           // 89*9 chunks = 6408 B
  float* W1s     = (float*)smem;           // phase T (reuses smem)
  float* W2s     = W1s + H0 * H1;
  float* scale_s = W2s + H1 * NOUT;
  float* shift_s = scale_s + H1;

  int t = threadIdx.x;
  int w = t >> 6, lane = t & 63, j = lane >> 3, q = lane & 7;
  int nbase = blockIdx.x * 16 + w * 4;

  float dd[4]; float4 acc[4];
  #pragma unroll
  for (int i = 0; i < 4; ++i) {
    dd[i] = dinv[nbase + i];
    acc[i] = make_float4(0.f, 0.f, 0.f, 0.f);
  }

  // fill A: Wexp k=0..7 (fp16) + bexp (fp16)
  for (int idx = t; idx < 89 * 64; idx += 256) {
    int v = idx >> 6, rem = idx & 63, kk = rem >> 3, qq = rem & 7;
    float4 s4 = *(const float4*)(Wexp + (size_t)kk * (NV * H0) + v * 32 + qq * 4);
    h4 o; o.a = __floats2half2_rn(s4.x, s4.y); o.b = __floats2half2_rn(s4.z, s4.w);
    Wh[v * 65 + kk * 8 + qq] = o;
  }
  for (int idx = t; idx < 89 * 8; idx += 256) {
    int v = idx >> 3, qq = idx & 7;
    float4 s4 = *(const float4*)(bexp + v * 32 + qq * 4);
    h4 o; o.a = __floats2half2_rn(s4.x, s4.y); o.b = __floats2half2_rn(s4.z, s4.w);
    bxh[v * 9 + qq] = o;
  }
  __syncthreads();
  #pragma unroll
  for (int i = 0; i < 4; ++i)
    edge_pass<0>(nbase + i, lane, j, q, rowptr, recs, dinv, ge, Wh, bxh, dd[i], acc[i]);
  __syncthreads();

  // fill B: Wexp k=8..15
  for (int idx = t; idx < 89 * 64; idx += 256) {
    int v = idx >> 6, rem = idx & 63, kk = rem >> 3, qq = rem & 7;
    float4 s4 = *(const float4*)(Wexp + (size_t)(8 + kk) * (NV * H0) + v * 32 + qq * 4);
    h4 o; o.a = __floats2half2_rn(s4.x, s4.y); o.b = __floats2half2_rn(s4.z, s4.w);
    Wh[v * 65 + kk * 8 + qq] = o;
  }
  __syncthreads();
  #pragma unroll
  for (int i = 0; i < 4; ++i)
    edge_pass<1>(nbase + i, lane, j, q, rowptr, recs, dinv, ge, Wh, bxh, dd[i], acc[i]);
  __syncthreads();

  // fill T: transform weights
  for (int idx = t; idx < H0 * H1; idx += 256) W1s[idx] = W1[idx];
  if (t < H1 * NOUT) W2s[t] = W2[t];
  if (t < H1) {
    float sc = gamma[t] * rsqrtf(var[t] + BN_EPS);
    scale_s[t] = sc;
    shift_s[t] = beta[t] + (b1[t] - mean[t]) * sc;
  }
  __syncthreads();

  // transform per node
  #pragma unroll
  for (int i = 0; i < 4; ++i) {
    float4 a = acc[i];
    #pragma unroll
    for (int off = 8; off < 64; off <<= 1) {
      a.x += __shfl_xor(a.x, off); a.y += __shfl_xor(a.y, off);
      a.z += __shfl_xor(a.z, off); a.w += __shfl_xor(a.w, off);
    }
    int srcl = (lane & 31) >> 2;
    float a0 = __shfl(a.x, srcl), a1 = __shfl(a.y, srcl),
          a2 = __shfl(a.z, srcl), a3 = __shfl(a.w, srcl);
    int c4 = lane & 3;
    float tk = (c4 == 0) ? a0 : (c4 == 1) ? a1 : (c4 == 2) ? a2 : a3;
    tk *= dd[i];
    float y = 0.f;
    #pragma unroll
    for (int kk = 0; kk < H0; ++kk) y += __shfl(tk, kk) * W1s[kk * H1 + lane];
    y = fmaxf(y * scale_s[lane] + shift_s[lane], 0.f);
    float p0 = y * W2s[lane * 3 + 0];
    float p1 = y * W2s[lane * 3 + 1];
    float p2 = y * W2s[lane * 3 + 2];
    #pragma unroll
    for (int off = 32; off; off >>= 1) {
      p0 += __shfl_xor(p0, off);
      p1 += __shfl_xor(p1, off);
      p2 += __shfl_xor(p2, off);
    }
    if (lane == 0) {
      float* zp = z + (size_t)(nbase + i) * 4;
      zp[0] = p0; zp[1] = p1; zp[2] = p2; zp[3] = 0.f;
    }
  }
}

// ---- layer 2: 4 lanes/node gather of z -> out ----
__global__ __launch_bounds__(256) void k_g2(
    const int* __restrict__ rowptr, const uint2* __restrict__ recs,
    const float* __restrict__ dinv, const float* __restrict__ z,
    const float* __restrict__ b2, float* __restrict__ out) {
  int t = threadIdx.x;
  int wave = t >> 6, lane = t & 63;
  int nw = lane >> 2, q = lane & 3;
  int n = blockIdx.x * 64 + wave * 16 + nw;
  int beg = rowptr[n], end = rowptr[n + 1];
  float a0 = 0.f, a1 = 0.f, a2 = 0.f;
  for (int i = beg + q; i < end; i += 4) {
    uint2 r = recs[i];
    int s = (int)(r.x >> 8);
    float f = dinv[s] * __uint_as_float(r.y);
    const float4 zv = *(const float4*)(z + (size_t)s * 4);
    a0 += f * zv.x; a1 += f * zv.y; a2 += f * zv.z;
  }
  a0 += __shfl_xor(a0, 1); a0 += __shfl_xor(a0, 2);
  a1 += __shfl_xor(a1, 1); a1 += __shfl_xor(a1, 2);
  a2 += __shfl_xor(a2, 1); a2 += __shfl_xor(a2, 2);
  if (q == 0) {
    float dd = dinv[n];
    const float4 zn = *(const float4*)(z + (size_t)n * 4);
    float* op = out + (size_t)n * 3;
    op[0] = b2[0] + dd * (a0 + dd * zn.x);
    op[1] = b2[1] + dd * (a1 + dd * zn.y);
    op[2] = b2[2] + dd * (a2 + dd * zn.z);
  }
}

extern "C" void kernel_launch(void* const* d_in, const int* in_sizes, int n_in,
                              void* d_out, int out_size, void* d_ws, size_t ws_size,
                              hipStream_t stream) {
  const float* ge   = (const float*)d_in[0];
  const int*   ei   = (const int*)d_in[1];
  const float* ew   = (const float*)d_in[2];
  const float* Wexp = (const float*)d_in[3];
  const float* bexp = (const float*)d_in[4];
  const float* W1   = (const float*)d_in[5];
  const float* b1   = (const float*)d_in[6];
  const float* W2   = (const float*)d_in[7];
  const float* b2   = (const float*)d_in[8];
  const float* gam  = (const float*)d_in[9];
  const float* bet  = (const float*)d_in[10];
  const float* mu   = (const float*)d_in[11];
  const float* var  = (const float*)d_in[12];
  const int* src = ei;
  const int* dst = ei + NEdg;
  float* out = (float*)d_out;

  // workspace (everything fully overwritten before read -> no memset)
  uint2*  recs   = (uint2*)d_ws;                         // NEdg * 8B
  uint2*  recs2  = recs + NEdg;                          // NEdg * 8B
  float*  dinv   = (float*)(recs2 + NEdg);               // NN
  float*  z      = dinv + NN;                            // NN*4 (padded)
  int*    rowptr = (int*)(z + (size_t)NN * 4);           // NN+1
  int*    blkOff = rowptr + NN + 1;                      // NBKT*NBKT
  int*    bktCnt = blkOff + (size_t)NBKT * NBKT;         // NBKT
  int*    bktPtr = bktCnt + NBKT;                        // NBKT

  k_hist   <<<NBKT, 256, 0, stream>>>(dst, blkOff);
  k_colscan<<<NBKT, 256, 0, stream>>>(blkOff, bktCnt);
  k_scanB  <<<1, 1024, 0, stream>>>(bktCnt, bktPtr);
  k_scat   <<<NBKT, 256, 0, stream>>>(src, dst, ew, blkOff, bktPtr, recs);
  k_sort2  <<<NBKT, 256, 0, stream>>>(bktPtr, bktCnt, recs, recs2, rowptr, dinv);
  k_e1     <<<NN / 16, 256, 0, stream>>>(rowptr, recs2, dinv, ge, Wexp, bexp,
                                         W1, b1, W2, gam, bet, mu, var, z);
  k_g2     <<<NN / 64, 256, 0, stream>>>(rowptr, recs2, dinv, z, b2, out);
}

// Round 8
// 333.822 us; speedup vs baseline: 1.7274x; 1.7274x over previous
//
#include <hip/hip_runtime.h>
#include <hip/hip_fp16.h>

constexpr int NB   = 2048;
constexpr int EMB  = 16;
constexpr int NV   = 89;
constexpr int NN   = NB * NV;      // 182272 nodes (= 712 * 256)
constexpr int NEdg = 16 * NN;      // 2916352 edges (= 712 * 4096)
constexpr int H0   = 32;
constexpr int H1   = 64;
constexpr int NOUT = 3;
constexpr int NBKT = NN / 256;     // 712 buckets of 256 nodes
constexpr int EPB  = NEdg / NBKT;  // 4096 edges per hist/scatter block
constexpr float BN_EPS = 1e-5f;

struct __align__(8) h4 { __half2 a, b; };

// ---- pass A: per-block LDS histogram -> blkOff[block][bucket] ----
__global__ __launch_bounds__(256) void k_hist(const int* __restrict__ dst,
                                              int* __restrict__ blkOff) {
  __shared__ int h[NBKT];
  int t = threadIdx.x, b = blockIdx.x;
  for (int i = t; i < NBKT; i += 256) h[i] = 0;
  __syncthreads();
  int base = b * EPB;
  #pragma unroll
  for (int k = 0; k < EPB / 256; ++k)
    atomicAdd(&h[dst[base + t + k * 256] >> 8], 1);
  __syncthreads();
  for (int i = t; i < NBKT; i += 256) blkOff[(size_t)b * NBKT + i] = h[i];
}

// ---- per-bucket column scan over blocks; bktCnt = totals ----
__global__ __launch_bounds__(256) void k_colscan(int* __restrict__ blkOff,
                                                 int* __restrict__ bktCnt) {
  __shared__ int s[256];
  int t = threadIdx.x, k = blockIdx.x;
  int b0 = t * 3;
  int v0 = (b0     < NBKT) ? blkOff[(size_t)(b0    ) * NBKT + k] : 0;
  int v1 = (b0 + 1 < NBKT) ? blkOff[(size_t)(b0 + 1) * NBKT + k] : 0;
  int v2 = (b0 + 2 < NBKT) ? blkOff[(size_t)(b0 + 2) * NBKT + k] : 0;
  int ts = v0 + v1 + v2;
  s[t] = ts;
  __syncthreads();
  for (int off = 1; off < 256; off <<= 1) {
    int a = (t >= off) ? s[t - off] : 0;
    __syncthreads();
    s[t] += a;
    __syncthreads();
  }
  int pre = s[t] - ts;
  if (b0     < NBKT) blkOff[(size_t)(b0    ) * NBKT + k] = pre;
  if (b0 + 1 < NBKT) blkOff[(size_t)(b0 + 1) * NBKT + k] = pre + v0;
  if (b0 + 2 < NBKT) blkOff[(size_t)(b0 + 2) * NBKT + k] = pre + v0 + v1;
  if (t == 255) bktCnt[k] = s[255];
}

// ---- bucket scan: bktCnt -> bktPtr (exclusive) ----
__global__ void k_scanB(const int* __restrict__ bktCnt, int* __restrict__ bktPtr) {
  __shared__ int s[1024];
  int t = threadIdx.x;
  int v = (t < NBKT) ? bktCnt[t] : 0;
  s[t] = v;
  __syncthreads();
  for (int off = 1; off < 1024; off <<= 1) {
    int a = (t >= off) ? s[t - off] : 0;
    __syncthreads();
    s[t] += a;
    __syncthreads();
  }
  if (t < NBKT) bktPtr[t] = s[t] - v;
}

// ---- pass B: place records bucket-grouped (LDS cursors only) ----
__global__ __launch_bounds__(256) void k_scat(const int* __restrict__ src,
                                              const int* __restrict__ dst,
                                              const float* __restrict__ ew,
                                              const int* __restrict__ blkOff,
                                              const int* __restrict__ bktPtr,
                                              uint2* __restrict__ recs) {
  __shared__ int cur[NBKT];
  int t = threadIdx.x, b = blockIdx.x;
  for (int i = t; i < NBKT; i += 256)
    cur[i] = bktPtr[i] + blkOff[(size_t)b * NBKT + i];
  __syncthreads();
  int base = b * EPB;
  #pragma unroll
  for (int k = 0; k < EPB / 256; ++k) {
    int e = base + t + k * 256;
    int d = dst[e];
    int p = atomicAdd(&cur[d >> 8], 1);
    recs[p] = make_uint2(((unsigned)src[e] << 8) | (unsigned)(d & 255),
                         __float_as_uint(ew[e]));
  }
}

// ---- pass C: in-bucket sort by node -> recs2 + rowptr + fused degree->dinv ----
__global__ __launch_bounds__(256) void k_sort2(
    const int* __restrict__ bktPtr, const int* __restrict__ bktCnt,
    const uint2* __restrict__ recs,
    uint2* __restrict__ recs2, int* __restrict__ rowptr,
    float* __restrict__ dinv) {
  __shared__ int sc[256];
  __shared__ int cur[256];
  __shared__ float dg[256];
  int t = threadIdx.x, k = blockIdx.x;
  sc[t] = 0;
  dg[t] = 0.f;
  __syncthreads();
  int beg = bktPtr[k], cnt = bktCnt[k];
  for (int i = t; i < cnt; i += 256) {
    uint2 r = recs[beg + i];
    atomicAdd(&sc[r.x & 255], 1);
    atomicAdd(&dg[r.x & 255], __uint_as_float(r.y));
  }
  __syncthreads();
  dinv[k * 256 + t] = rsqrtf(dg[t] + 1.0f);
  int v = sc[t];
  __syncthreads();
  sc[t] = v;
  __syncthreads();
  for (int off = 1; off < 256; off <<= 1) {
    int a = (t >= off) ? sc[t - off] : 0;
    __syncthreads();
    sc[t] += a;
    __syncthreads();
  }
  int excl = beg + sc[t] - v;
  cur[t] = excl;
  rowptr[k * 256 + t] = excl;
  if (k == NBKT - 1 && t == 0) rowptr[NN] = NEdg;
  __syncthreads();
  for (int i = t; i < cnt; i += 256) {
    uint2 r = recs[beg + i];
    int p = atomicAdd(&cur[r.x & 255], 1);
    recs2[p] = r;                      // raw {src<<8|row, w}
  }
}

// ---- expand: x[n][0:32] fp16 ----
__global__ void k_expand(const float* __restrict__ ge, const float* __restrict__ Wexp,
                         const float* __restrict__ bexp, __half* __restrict__ xh) {
  int tid = blockIdx.x * 256 + threadIdx.x;
  if (tid >= NN * 8) return;
  int n = tid >> 3, q = tid & 7;
  int g = n / NV, v = n - g * NV;
  int col = v * H0 + q * 4;
  float4 acc = *(const float4*)(bexp + col);
  const float* gp = ge + g * EMB;
  #pragma unroll
  for (int k = 0; k < EMB; ++k) {
    float gk = gp[k];
    float4 w = *(const float4*)(Wexp + (size_t)k * (NV * H0) + col);
    acc.x += gk * w.x; acc.y += gk * w.y; acc.z += gk * w.z; acc.w += gk * w.w;
  }
  h4 o;
  o.a = __floats2half2_rn(acc.x, acc.y);
  o.b = __floats2half2_rn(acc.z, acc.w);
  *(h4*)(xh + (size_t)n * H0 + q * 4) = o;
}

// accumulate one 16B x-chunk (8 fp16 feats) into a[8]
__device__ __forceinline__ void acc_chunk(float4 tmp, float fj, float* a) {
  const __half2* hp = (const __half2*)&tmp;
  #pragma unroll
  for (int u = 0; u < 4; ++u) {
    float2 xy = __half22float2(hp[u]);
    a[2 * u]     += fj * xy.x;
    a[2 * u + 1] += fj * xy.y;
  }
}

// ---- layer 1: MLP-optimized gather + fused W1/BN/ReLU/W2 -> z[N,4] ----
// wave = 4 nodes; lane = edge-slot j (16) x row-quarter q (4); self-loop = idx 0
__global__ __launch_bounds__(256) void k_g1(
    const int* __restrict__ rowptr, const uint2* __restrict__ recs,
    const float* __restrict__ dinv, const __half* __restrict__ xh,
    const float* __restrict__ W1, const float* __restrict__ b1,
    const float* __restrict__ W2,
    const float* __restrict__ gamma, const float* __restrict__ beta,
    const float* __restrict__ mean, const float* __restrict__ var,
    float* __restrict__ z) {
  __shared__ float W1s[H0 * H1];
  __shared__ float W2s[H1 * NOUT];
  __shared__ float scale_s[H1], shift_s[H1];
  int t = threadIdx.x;
  for (int i = t; i < H0 * H1; i += 256) W1s[i] = W1[i];
  if (t < H1 * NOUT) W2s[t] = W2[t];
  if (t < H1) {
    float sc = gamma[t] * rsqrtf(var[t] + BN_EPS);
    scale_s[t] = sc;
    shift_s[t] = beta[t] + (b1[t] - mean[t]) * sc;
  }
  __syncthreads();
  int w = t >> 6, lane = t & 63;
  int j = lane >> 2, q = lane & 3;
  int nbase = blockIdx.x * 16 + w * 4;

  // phase 1: prefetch recs (idx 0 = self; idx 1..cnt = edges; else f=0)
  int rs[4]; float rf[4]; int tot[4]; int beg[4];
  #pragma unroll
  for (int i = 0; i < 4; ++i) {
    int n = nbase + i;
    beg[i] = rowptr[n];
    int cnt = rowptr[n + 1] - beg[i];
    tot[i] = cnt + 1;
    rs[i] = n; rf[i] = 0.f;
    if (lane >= 1 && lane < tot[i]) {
      uint2 r = recs[beg[i] + lane - 1];
      rs[i] = (int)(r.x >> 8);
      rf[i] = __uint_as_float(r.y);
    }
  }
  #pragma unroll
  for (int i = 0; i < 4; ++i) {
    float dv = dinv[rs[i]];
    rf[i] = (lane == 0) ? dv : dv * rf[i];   // lane0: dd; invalid lanes: 0
  }

  // phase 2: chunks 0,1 (covers tot<=32) — issue ALL loads before FMAs
  float a[4][8];
  #pragma unroll
  for (int i = 0; i < 4; ++i)
    #pragma unroll
    for (int r = 0; r < 8; ++r) a[i][r] = 0.f;

  {
    float4 tmp[4][2];
    #pragma unroll
    for (int i = 0; i < 4; ++i)
      #pragma unroll
      for (int c = 0; c < 2; ++c) {
        int sj = __shfl(rs[i], c * 16 + j);
        tmp[i][c] = *((const float4*)(xh + (size_t)sj * H0) + q);
      }
    #pragma unroll
    for (int i = 0; i < 4; ++i)
      #pragma unroll
      for (int c = 0; c < 2; ++c)
        acc_chunk(tmp[i][c], __shfl(rf[i], c * 16 + j), a[i]);
  }
  // rare tail: chunks 2,3 (tot<=64; f=0 lanes harmless)
  #pragma unroll
  for (int i = 0; i < 4; ++i) {
    if (tot[i] > 32) {
      float4 tmp[2];
      #pragma unroll
      for (int c = 2; c < 4; ++c) {
        int sj = __shfl(rs[i], c * 16 + j);
        tmp[c - 2] = *((const float4*)(xh + (size_t)sj * H0) + q);
      }
      #pragma unroll
      for (int c = 2; c < 4; ++c)
        acc_chunk(tmp[c - 2], __shfl(rf[i], c * 16 + j), a[i]);
    }
    // ultra-cold: deg > 63 (P ~ 1e-14) — direct per-edge loads
    if (tot[i] > 64) {
      for (int idx = 64 + j; idx < tot[i]; idx += 16) {
        uint2 r = recs[beg[i] + idx - 1];
        int s = (int)(r.x >> 8);
        float f = dinv[s] * __uint_as_float(r.y);
        float4 xv = *((const float4*)(xh + (size_t)s * H0) + q);
        acc_chunk(xv, f, a[i]);
      }
    }
  }

  // phase 3: reduce over the 16 edge-slots (xor on lane bits 2..5)
  #pragma unroll
  for (int i = 0; i < 4; ++i)
    #pragma unroll
    for (int r = 0; r < 8; ++r) {
      float v = a[i][r];
      v += __shfl_xor(v, 4);
      v += __shfl_xor(v, 8);
      v += __shfl_xor(v, 16);
      v += __shfl_xor(v, 32);
      a[i][r] = v;
    }

  // phase 4: transform per node (t_k read via shfl(a[k&7], k>>3))
  #pragma unroll
  for (int i = 0; i < 4; ++i) {
    float dd = __shfl(rf[i], 0);
    float y = 0.f;
    #pragma unroll
    for (int kk = 0; kk < H0; ++kk)
      y += __shfl(a[i][kk & 7], kk >> 3) * W1s[kk * H1 + lane];
    y = fmaxf(y * (dd * scale_s[lane]) + shift_s[lane], 0.f);
    float p0 = y * W2s[lane * 3 + 0];
    float p1 = y * W2s[lane * 3 + 1];
    float p2 = y * W2s[lane * 3 + 2];
    #pragma unroll
    for (int off = 32; off; off >>= 1) {
      p0 += __shfl_xor(p0, off);
      p1 += __shfl_xor(p1, off);
      p2 += __shfl_xor(p2, off);
    }
    if (lane == 0)
      *(float4*)(z + (size_t)(nbase + i) * 4) = make_float4(p0, p1, p2, 0.f);
  }
}

// ---- layer 2: wave = 4 nodes x 16 lanes, lane owns edges (no shuffles) ----
__global__ __launch_bounds__(256) void k_g2(
    const int* __restrict__ rowptr, const uint2* __restrict__ recs,
    const float* __restrict__ dinv, const float* __restrict__ z,
    const float* __restrict__ b2, float* __restrict__ out) {
  int t = threadIdx.x;
  int w = t >> 6, lane = t & 63;
  int si = lane >> 4, j = lane & 15;
  int n = blockIdx.x * 16 + w * 4 + si;
  int beg = rowptr[n];
  int tot = rowptr[n + 1] - beg + 1;          // + self at idx 0
  // prefetch 2 edges per lane (covers tot<=32)
  int s0 = n, s1 = n; float f0 = 0.f, f1 = 0.f;
  if (j >= 1 && j < tot) {                     // idx = j
    uint2 r = recs[beg + j - 1];
    s0 = (int)(r.x >> 8); f0 = __uint_as_float(r.y);
  }
  if (j + 16 < tot) {                          // idx = j+16
    uint2 r = recs[beg + j + 15];
    s1 = (int)(r.x >> 8); f1 = __uint_as_float(r.y);
  }
  float dv0 = dinv[s0], dv1 = dinv[s1];
  f0 = (j == 0) ? dv0 : dv0 * f0;
  f1 = dv1 * f1;
  float4 z0 = *(const float4*)(z + (size_t)s0 * 4);
  float4 z1 = *(const float4*)(z + (size_t)s1 * 4);
  float a0 = f0 * z0.x + f1 * z1.x;
  float a1 = f0 * z0.y + f1 * z1.y;
  float a2 = f0 * z0.z + f1 * z1.z;
  // ultra-cold tail
  if (tot > 32) {
    for (int idx = 32 + j; idx < tot; idx += 16) {
      uint2 r = recs[beg + idx - 1];
      int s = (int)(r.x >> 8);
      float f = dinv[s] * __uint_as_float(r.y);
      const float4 zv = *(const float4*)(z + (size_t)s * 4);
      a0 += f * zv.x; a1 += f * zv.y; a2 += f * zv.z;
    }
  }
  a0 += __shfl_xor(a0, 1); a1 += __shfl_xor(a1, 1); a2 += __shfl_xor(a2, 1);
  a0 += __shfl_xor(a0, 2); a1 += __shfl_xor(a1, 2); a2 += __shfl_xor(a2, 2);
  a0 += __shfl_xor(a0, 4); a1 += __shfl_xor(a1, 4); a2 += __shfl_xor(a2, 4);
  a0 += __shfl_xor(a0, 8); a1 += __shfl_xor(a1, 8); a2 += __shfl_xor(a2, 8);
  if (j == 0) {
    float dd = dv0;                            // dinv[n]
    float* op = out + (size_t)n * 3;
    op[0] = b2[0] + dd * a0;
    op[1] = b2[1] + dd * a1;
    op[2] = b2[2] + dd * a2;
  }
}

extern "C" void kernel_launch(void* const* d_in, const int* in_sizes, int n_in,
                              void* d_out, int out_size, void* d_ws, size_t ws_size,
                              hipStream_t stream) {
  const float* ge   = (const float*)d_in[0];
  const int*   ei   = (const int*)d_in[1];
  const float* ew   = (const float*)d_in[2];
  const float* Wexp = (const float*)d_in[3];
  const float* bexp = (const float*)d_in[4];
  const float* W1   = (const float*)d_in[5];
  const float* b1   = (const float*)d_in[6];
  const float* W2   = (const float*)d_in[7];
  const float* b2   = (const float*)d_in[8];
  const float* gam  = (const float*)d_in[9];
  const float* bet  = (const float*)d_in[10];
  const float* mu   = (const float*)d_in[11];
  const float* var  = (const float*)d_in[12];
  const int* src = ei;
  const int* dst = ei + NEdg;
  float* out = (float*)d_out;

  // workspace (everything fully overwritten before read -> no memset)
  uint2*  recs   = (uint2*)d_ws;                         // NEdg * 8B
  uint2*  recs2  = recs + NEdg;                          // NEdg * 8B
  float*  dinv   = (float*)(recs2 + NEdg);               // NN
  __half* xh     = (__half*)(dinv + NN);                 // NN*32 fp16
  float*  z      = (float*)(xh + (size_t)NN * H0);       // NN*4 (padded)
  int*    rowptr = (int*)(z + (size_t)NN * 4);           // NN+1
  int*    blkOff = rowptr + NN + 1;                      // NBKT*NBKT
  int*    bktCnt = blkOff + (size_t)NBKT * NBKT;         // NBKT
  int*    bktPtr = bktCnt + NBKT;                        // NBKT

  k_hist   <<<NBKT, 256, 0, stream>>>(dst, blkOff);
  k_colscan<<<NBKT, 256, 0, stream>>>(blkOff, bktCnt);
  k_scanB  <<<1, 1024, 0, stream>>>(bktCnt, bktPtr);
  k_scat   <<<NBKT, 256, 0, stream>>>(src, dst, ew, blkOff, bktPtr, recs);
  k_sort2  <<<NBKT, 256, 0, stream>>>(bktPtr, bktCnt, recs, recs2, rowptr, dinv);
  k_expand <<<NN * 8 / 256, 256, 0, stream>>>(ge, Wexp, bexp, xh);
  k_g1     <<<NN / 16, 256, 0, stream>>>(rowptr, recs2, dinv, xh,
                                         W1, b1, W2, gam, bet, mu, var, z);
  k_g2     <<<NN / 16, 256, 0, stream>>>(rowptr, recs2, dinv, z, b2, out);
}

// Round 9
// 329.636 us; speedup vs baseline: 1.7493x; 1.0127x over previous
//
#include <hip/hip_runtime.h>
#include <hip/hip_fp16.h>

constexpr int NB   = 2048;
constexpr int EMB  = 16;
constexpr int NV   = 89;
constexpr int NN   = NB * NV;      // 182272 nodes (= 712 * 256 = 2848 * 64)
constexpr int NEdg = 16 * NN;      // 2916352 edges (= 712 * 4096)
constexpr int H0   = 32;
constexpr int H1   = 64;
constexpr int NOUT = 3;
constexpr int NBKT = NN / 256;     // 712 buckets of 256 nodes
constexpr int EPB  = NEdg / NBKT;  // 4096 edges per hist/scatter block
constexpr float BN_EPS = 1e-5f;

struct __align__(8) h4 { __half2 a, b; };

// ---- pass A: per-block LDS histogram -> blkOff[block][bucket] ----
__global__ __launch_bounds__(256) void k_hist(const int* __restrict__ dst,
                                              int* __restrict__ blkOff) {
  __shared__ int h[NBKT];
  int t = threadIdx.x, b = blockIdx.x;
  for (int i = t; i < NBKT; i += 256) h[i] = 0;
  __syncthreads();
  int base = b * EPB;
  #pragma unroll
  for (int k = 0; k < EPB / 256; ++k)
    atomicAdd(&h[dst[base + t + k * 256] >> 8], 1);
  __syncthreads();
  for (int i = t; i < NBKT; i += 256) blkOff[(size_t)b * NBKT + i] = h[i];
}

// ---- per-bucket column scan over blocks; bktCnt = totals ----
__global__ __launch_bounds__(256) void k_colscan(int* __restrict__ blkOff,
                                                 int* __restrict__ bktCnt) {
  __shared__ int s[256];
  int t = threadIdx.x, k = blockIdx.x;
  int b0 = t * 3;
  int v0 = (b0     < NBKT) ? blkOff[(size_t)(b0    ) * NBKT + k] : 0;
  int v1 = (b0 + 1 < NBKT) ? blkOff[(size_t)(b0 + 1) * NBKT + k] : 0;
  int v2 = (b0 + 2 < NBKT) ? blkOff[(size_t)(b0 + 2) * NBKT + k] : 0;
  int ts = v0 + v1 + v2;
  s[t] = ts;
  __syncthreads();
  for (int off = 1; off < 256; off <<= 1) {
    int a = (t >= off) ? s[t - off] : 0;
    __syncthreads();
    s[t] += a;
    __syncthreads();
  }
  int pre = s[t] - ts;
  if (b0     < NBKT) blkOff[(size_t)(b0    ) * NBKT + k] = pre;
  if (b0 + 1 < NBKT) blkOff[(size_t)(b0 + 1) * NBKT + k] = pre + v0;
  if (b0 + 2 < NBKT) blkOff[(size_t)(b0 + 2) * NBKT + k] = pre + v0 + v1;
  if (t == 255) bktCnt[k] = s[255];
}

// ---- bucket scan: bktCnt -> bktPtr (exclusive) ----
__global__ void k_scanB(const int* __restrict__ bktCnt, int* __restrict__ bktPtr) {
  __shared__ int s[1024];
  int t = threadIdx.x;
  int v = (t < NBKT) ? bktCnt[t] : 0;
  s[t] = v;
  __syncthreads();
  for (int off = 1; off < 1024; off <<= 1) {
    int a = (t >= off) ? s[t - off] : 0;
    __syncthreads();
    s[t] += a;
    __syncthreads();
  }
  if (t < NBKT) bktPtr[t] = s[t] - v;
}

// ---- pass B: place records bucket-grouped (LDS cursors only) ----
__global__ __launch_bounds__(256) void k_scat(const int* __restrict__ src,
                                              const int* __restrict__ dst,
                                              const float* __restrict__ ew,
                                              const int* __restrict__ blkOff,
                                              const int* __restrict__ bktPtr,
                                              uint2* __restrict__ recs) {
  __shared__ int cur[NBKT];
  int t = threadIdx.x, b = blockIdx.x;
  for (int i = t; i < NBKT; i += 256)
    cur[i] = bktPtr[i] + blkOff[(size_t)b * NBKT + i];
  __syncthreads();
  int base = b * EPB;
  #pragma unroll
  for (int k = 0; k < EPB / 256; ++k) {
    int e = base + t + k * 256;
    int d = dst[e];
    int p = atomicAdd(&cur[d >> 8], 1);
    recs[p] = make_uint2(((unsigned)src[e] << 8) | (unsigned)(d & 255),
                         __float_as_uint(ew[e]));
  }
}

// ---- degree from bucket records -> dinv ----
__global__ __launch_bounds__(256) void k_deg2(const int* __restrict__ bktPtr,
                                              const int* __restrict__ bktCnt,
                                              const uint2* __restrict__ recs,
                                              float* __restrict__ dinv) {
  __shared__ float dg[256];
  int t = threadIdx.x, k = blockIdx.x;
  dg[t] = 0.f;
  __syncthreads();
  int beg = bktPtr[k], end = beg + bktCnt[k];
  for (int i = beg + t; i < end; i += 256) {
    uint2 r = recs[i];
    atomicAdd(&dg[r.x & 255], __uint_as_float(r.y));
  }
  __syncthreads();
  dinv[k * 256 + t] = rsqrtf(dg[t] + 1.0f);
}

// ---- pass C: in-bucket sort by node -> recs2 (f = dinv[s]*w premult) + rowptr ----
__global__ __launch_bounds__(256) void k_sort2(
    const int* __restrict__ bktPtr, const int* __restrict__ bktCnt,
    const uint2* __restrict__ recs, const float* __restrict__ dinv,
    uint2* __restrict__ recs2, int* __restrict__ rowptr) {
  __shared__ int sc[256];
  __shared__ int cur[256];
  int t = threadIdx.x, k = blockIdx.x;
  sc[t] = 0;
  __syncthreads();
  int beg = bktPtr[k], cnt = bktCnt[k];
  for (int i = t; i < cnt; i += 256)
    atomicAdd(&sc[recs[beg + i].x & 255], 1);
  __syncthreads();
  int v = sc[t];
  __syncthreads();
  sc[t] = v;
  __syncthreads();
  for (int off = 1; off < 256; off <<= 1) {
    int a = (t >= off) ? sc[t - off] : 0;
    __syncthreads();
    sc[t] += a;
    __syncthreads();
  }
  int excl = beg + sc[t] - v;
  cur[t] = excl;
  rowptr[k * 256 + t] = excl;
  if (k == NBKT - 1 && t == 0) rowptr[NN] = NEdg;
  __syncthreads();
  for (int i = t; i < cnt; i += 256) {
    uint2 r = recs[beg + i];
    int p = atomicAdd(&cur[r.x & 255], 1);
    int s = (int)(r.x >> 8);
    recs2[p] = make_uint2(r.x, __float_as_uint(dinv[s] * __uint_as_float(r.y)));
  }
}

// ---- expand: x[n][0:32] fp16 ----
__global__ void k_expand(const float* __restrict__ ge, const float* __restrict__ Wexp,
                         const float* __restrict__ bexp, __half* __restrict__ xh) {
  int tid = blockIdx.x * 256 + threadIdx.x;
  if (tid >= NN * 8) return;
  int n = tid >> 3, q = tid & 7;
  int g = n / NV, v = n - g * NV;
  int col = v * H0 + q * 4;
  float4 acc = *(const float4*)(bexp + col);
  const float* gp = ge + g * EMB;
  #pragma unroll
  for (int k = 0; k < EMB; ++k) {
    float gk = gp[k];
    float4 w = *(const float4*)(Wexp + (size_t)k * (NV * H0) + col);
    acc.x += gk * w.x; acc.y += gk * w.y; acc.z += gk * w.z; acc.w += gk * w.w;
  }
  h4 o;
  o.a = __floats2half2_rn(acc.x, acc.y);
  o.b = __floats2half2_rn(acc.z, acc.w);
  *(h4*)(xh + (size_t)n * H0 + q * 4) = o;
}

// accumulate one 16B x-chunk (8 fp16 feats) into a[8]
__device__ __forceinline__ void acc_chunk(float4 tmp, float fj, float* a) {
  const __half2* hp = (const __half2*)&tmp;
  #pragma unroll
  for (int u = 0; u < 4; ++u) {
    float2 xy = __half22float2(hp[u]);
    a[2 * u]     += fj * xy.x;
    a[2 * u + 1] += fj * xy.y;
  }
}

// ---- pure gather: agg[n][0:32] = dinv[n]*x[n] + sum_e f_e * x[s_e]  (no dd yet)
// wave = 16 nodes x 4 lanes (lane owns row-quarter q). Zero LDS, zero reduce.
__global__ __launch_bounds__(256) void k_agg(
    const int* __restrict__ rowptr, const uint2* __restrict__ recs,
    const float* __restrict__ dinv, const __half* __restrict__ xh,
    float* __restrict__ agg) {
  int t = threadIdx.x;
  int w = t >> 6, lane = t & 63;
  int grp = lane >> 2, q = lane & 3;
  int nbase = blockIdx.x * 64 + w * 16;

  int rp   = (lane < 17) ? rowptr[nbase + lane] : 0;
  float dv = (lane < 16) ? dinv[nbase + lane] : 0.f;
  int beg = __shfl(rp, grp);
  int cnt = __shfl(rp, grp + 1) - beg;
  float dd = __shfl(dv, grp);
  int n = nbase + grp;
  int tot = cnt + 1;                    // idx 0 = self loop

  float a[8];
  #pragma unroll
  for (int r = 0; r < 8; ++r) a[r] = 0.f;

  // round-0 rec (idx = q): q==0 -> self
  int rs = n; float rf = dd;
  if (q > 0) {
    if (q < tot) {
      uint2 rr = recs[beg + q - 1];
      rs = (int)(rr.x >> 8);
      rf = __uint_as_float(rr.y);
    } else rf = 0.f;
  }

  int rounds = (tot + 3) >> 2;
  for (int r = 0; r < rounds; ++r) {
    // prefetch next round's rec
    int rs_n = 0; float rf_n = 0.f;
    int idx_n = (r + 1) * 4 + q;
    if (idx_n < tot) {
      uint2 rr = recs[beg + idx_n - 1];
      rs_n = (int)(rr.x >> 8);
      rf_n = __uint_as_float(rr.y);
    }
    int base = r * 4;
    int nv = tot - base; nv = nv < 4 ? nv : 4;
    int ss[4]; float ff[4];
    #pragma unroll
    for (int k = 0; k < 4; ++k) {
      ss[k] = __shfl(rs, grp * 4 + k);
      ff[k] = __shfl(rf, grp * 4 + k);
    }
    float4 xv[4];
    #pragma unroll
    for (int k = 0; k < 4; ++k)
      if (k < nv) xv[k] = *((const float4*)(xh + (size_t)ss[k] * H0) + q);
    #pragma unroll
    for (int k = 0; k < 4; ++k)
      if (k < nv) acc_chunk(xv[k], ff[k], a);
    rs = rs_n; rf = rf_n;
  }

  float* ap = agg + (size_t)n * H0 + q * 8;
  *(float4*)(ap)     = make_float4(a[0], a[1], a[2], a[3]);
  *(float4*)(ap + 4) = make_float4(a[4], a[5], a[6], a[7]);
}

// ---- transform: z = W2^T(ReLU(BN(dd*agg @ W1 + b1))) ; wave = 4 nodes ----
__global__ __launch_bounds__(256) void k_trans(
    const float* __restrict__ agg, const float* __restrict__ dinv,
    const float* __restrict__ W1, const float* __restrict__ b1,
    const float* __restrict__ W2,
    const float* __restrict__ gamma, const float* __restrict__ beta,
    const float* __restrict__ mean, const float* __restrict__ var,
    float* __restrict__ z) {
  __shared__ float W1s[H0 * H1];
  __shared__ float W2s[H1 * NOUT];
  __shared__ float scale_s[H1], shift_s[H1];
  int t = threadIdx.x;
  for (int i = t; i < H0 * H1; i += 256) W1s[i] = W1[i];
  if (t < H1 * NOUT) W2s[t] = W2[t];
  if (t < H1) {
    float sc = gamma[t] * rsqrtf(var[t] + BN_EPS);
    scale_s[t] = sc;
    shift_s[t] = beta[t] + (b1[t] - mean[t]) * sc;
  }
  int w = t >> 6, lane = t & 63;
  int nbase = blockIdx.x * 16 + w * 4;
  float dv = (lane < 4) ? dinv[nbase + lane] : 0.f;
  float tk[4];
  #pragma unroll
  for (int i = 0; i < 4; ++i)
    tk[i] = (lane < 32) ? agg[(size_t)(nbase + i) * H0 + lane] : 0.f;
  __syncthreads();
  #pragma unroll
  for (int i = 0; i < 4; ++i) {
    float dd = __shfl(dv, i);
    float tki = tk[i] * dd;
    float y = 0.f;
    #pragma unroll
    for (int kk = 0; kk < H0; ++kk)
      y += __shfl(tki, kk) * W1s[kk * H1 + lane];
    y = fmaxf(y * scale_s[lane] + shift_s[lane], 0.f);
    float p0 = y * W2s[lane * 3 + 0];
    float p1 = y * W2s[lane * 3 + 1];
    float p2 = y * W2s[lane * 3 + 2];
    #pragma unroll
    for (int off = 32; off; off >>= 1) {
      p0 += __shfl_xor(p0, off);
      p1 += __shfl_xor(p1, off);
      p2 += __shfl_xor(p2, off);
    }
    if (lane == 0)
      *(float4*)(z + (size_t)(nbase + i) * 4) = make_float4(p0, p1, p2, 0.f);
  }
}

// ---- layer 2: wave = 4 nodes x 16 lanes, premultiplied f ----
__global__ __launch_bounds__(256) void k_g2(
    const int* __restrict__ rowptr, const uint2* __restrict__ recs,
    const float* __restrict__ dinv, const float* __restrict__ z,
    const float* __restrict__ b2, float* __restrict__ out) {
  int t = threadIdx.x;
  int w = t >> 6, lane = t & 63;
  int si = lane >> 4, j = lane & 15;
  int n = blockIdx.x * 16 + w * 4 + si;
  int beg = rowptr[n];
  int tot = rowptr[n + 1] - beg + 1;          // + self at idx 0
  int s0 = n, s1 = n; float f0 = 0.f, f1 = 0.f, dd = 0.f;
  if (j == 0) {
    dd = dinv[n];
    f0 = dd;
  } else if (j < tot) {
    uint2 r = recs[beg + j - 1];
    s0 = (int)(r.x >> 8); f0 = __uint_as_float(r.y);
  }
  if (j + 16 < tot) {
    uint2 r = recs[beg + j + 15];
    s1 = (int)(r.x >> 8); f1 = __uint_as_float(r.y);
  }
  float4 z0 = *(const float4*)(z + (size_t)s0 * 4);
  float4 z1 = *(const float4*)(z + (size_t)s1 * 4);
  float a0 = f0 * z0.x + f1 * z1.x;
  float a1 = f0 * z0.y + f1 * z1.y;
  float a2 = f0 * z0.z + f1 * z1.z;
  if (tot > 32) {
    for (int idx = 32 + j; idx < tot; idx += 16) {
      uint2 r = recs[beg + idx - 1];
      int s = (int)(r.x >> 8);
      float f = __uint_as_float(r.y);
      const float4 zv = *(const float4*)(z + (size_t)s * 4);
      a0 += f * zv.x; a1 += f * zv.y; a2 += f * zv.z;
    }
  }
  a0 += __shfl_xor(a0, 1); a1 += __shfl_xor(a1, 1); a2 += __shfl_xor(a2, 1);
  a0 += __shfl_xor(a0, 2); a1 += __shfl_xor(a1, 2); a2 += __shfl_xor(a2, 2);
  a0 += __shfl_xor(a0, 4); a1 += __shfl_xor(a1, 4); a2 += __shfl_xor(a2, 4);
  a0 += __shfl_xor(a0, 8); a1 += __shfl_xor(a1, 8); a2 += __shfl_xor(a2, 8);
  if (j == 0) {
    float* op = out + (size_t)n * 3;
    op[0] = b2[0] + dd * a0;
    op[1] = b2[1] + dd * a1;
    op[2] = b2[2] + dd * a2;
  }
}

extern "C" void kernel_launch(void* const* d_in, const int* in_sizes, int n_in,
                              void* d_out, int out_size, void* d_ws, size_t ws_size,
                              hipStream_t stream) {
  const float* ge   = (const float*)d_in[0];
  const int*   ei   = (const int*)d_in[1];
  const float* ew   = (const float*)d_in[2];
  const float* Wexp = (const float*)d_in[3];
  const float* bexp = (const float*)d_in[4];
  const float* W1   = (const float*)d_in[5];
  const float* b1   = (const float*)d_in[6];
  const float* W2   = (const float*)d_in[7];
  const float* b2   = (const float*)d_in[8];
  const float* gam  = (const float*)d_in[9];
  const float* bet  = (const float*)d_in[10];
  const float* mu   = (const float*)d_in[11];
  const float* var  = (const float*)d_in[12];
  const int* src = ei;
  const int* dst = ei + NEdg;
  float* out = (float*)d_out;

  // workspace (everything fully overwritten before read -> no memset)
  uint2*  recs   = (uint2*)d_ws;                         // NEdg * 8B
  uint2*  recs2  = recs + NEdg;                          // NEdg * 8B
  float*  dinv   = (float*)(recs2 + NEdg);               // NN
  __half* xh     = (__half*)(dinv + NN);                 // NN*32 fp16
  float*  aggb   = (float*)(xh + (size_t)NN * H0);       // NN*32 fp32
  float*  z      = aggb + (size_t)NN * H0;               // NN*4 (padded)
  int*    rowptr = (int*)(z + (size_t)NN * 4);           // NN+1
  int*    blkOff = rowptr + NN + 1;                      // NBKT*NBKT
  int*    bktCnt = blkOff + (size_t)NBKT * NBKT;         // NBKT
  int*    bktPtr = bktCnt + NBKT;                        // NBKT

  k_hist   <<<NBKT, 256, 0, stream>>>(dst, blkOff);
  k_colscan<<<NBKT, 256, 0, stream>>>(blkOff, bktCnt);
  k_scanB  <<<1, 1024, 0, stream>>>(bktCnt, bktPtr);
  k_scat   <<<NBKT, 256, 0, stream>>>(src, dst, ew, blkOff, bktPtr, recs);
  k_deg2   <<<NBKT, 256, 0, stream>>>(bktPtr, bktCnt, recs, dinv);
  k_sort2  <<<NBKT, 256, 0, stream>>>(bktPtr, bktCnt, recs, dinv, recs2, rowptr);
  k_expand <<<NN * 8 / 256, 256, 0, stream>>>(ge, Wexp, bexp, xh);
  k_agg    <<<NN / 64, 256, 0, stream>>>(rowptr, recs2, dinv, xh, aggb);
  k_trans  <<<NN / 16, 256, 0, stream>>>(aggb, dinv, W1, b1, W2,
                                         gam, bet, mu, var, z);
  k_g2     <<<NN / 16, 256, 0, stream>>>(rowptr, recs2, dinv, z, b2, out);
}

// Round 10
// 217.887 us; speedup vs baseline: 2.6465x; 1.5129x over previous
//
#include <hip/hip_runtime.h>
#include <hip/hip_fp16.h>

constexpr int NB   = 2048;
constexpr int EMB  = 16;
constexpr int NV   = 89;
constexpr int NN   = NB * NV;      // 182272 nodes (= 712 * 256 = 2848 * 64)
constexpr int NEdg = 16 * NN;      // 2916352 edges (= 712 * 4096)
constexpr int H0   = 32;
constexpr int H1   = 64;
constexpr int NOUT = 3;
constexpr int NBKT = NN / 256;     // 712 buckets of 256 nodes
constexpr int EPB  = NEdg / NBKT;  // 4096 edges per hist/scatter block
constexpr float BN_EPS = 1e-5f;

struct __align__(8) h4 { __half2 a, b; };
typedef _Float16 half8_t __attribute__((ext_vector_type(8)));
typedef _Float16 half4_t __attribute__((ext_vector_type(4)));
typedef float floatx4 __attribute__((ext_vector_type(4)));

// ---- pass A: per-block LDS histogram -> blkOff[block][bucket] ----
__global__ __launch_bounds__(256) void k_hist(const int* __restrict__ dst,
                                              int* __restrict__ blkOff) {
  __shared__ int h[NBKT];
  int t = threadIdx.x, b = blockIdx.x;
  for (int i = t; i < NBKT; i += 256) h[i] = 0;
  __syncthreads();
  int base = b * EPB;
  #pragma unroll
  for (int k = 0; k < EPB / 256; ++k)
    atomicAdd(&h[dst[base + t + k * 256] >> 8], 1);
  __syncthreads();
  for (int i = t; i < NBKT; i += 256) blkOff[(size_t)b * NBKT + i] = h[i];
}

// ---- per-bucket column scan over blocks; bktCnt = totals ----
__global__ __launch_bounds__(256) void k_colscan(int* __restrict__ blkOff,
                                                 int* __restrict__ bktCnt) {
  __shared__ int s[256];
  int t = threadIdx.x, k = blockIdx.x;
  int b0 = t * 3;
  int v0 = (b0     < NBKT) ? blkOff[(size_t)(b0    ) * NBKT + k] : 0;
  int v1 = (b0 + 1 < NBKT) ? blkOff[(size_t)(b0 + 1) * NBKT + k] : 0;
  int v2 = (b0 + 2 < NBKT) ? blkOff[(size_t)(b0 + 2) * NBKT + k] : 0;
  int ts = v0 + v1 + v2;
  s[t] = ts;
  __syncthreads();
  for (int off = 1; off < 256; off <<= 1) {
    int a = (t >= off) ? s[t - off] : 0;
    __syncthreads();
    s[t] += a;
    __syncthreads();
  }
  int pre = s[t] - ts;
  if (b0     < NBKT) blkOff[(size_t)(b0    ) * NBKT + k] = pre;
  if (b0 + 1 < NBKT) blkOff[(size_t)(b0 + 1) * NBKT + k] = pre + v0;
  if (b0 + 2 < NBKT) blkOff[(size_t)(b0 + 2) * NBKT + k] = pre + v0 + v1;
  if (t == 255) bktCnt[k] = s[255];
}

// ---- bucket scan: bktCnt -> bktPtr (exclusive) ----
__global__ void k_scanB(const int* __restrict__ bktCnt, int* __restrict__ bktPtr) {
  __shared__ int s[1024];
  int t = threadIdx.x;
  int v = (t < NBKT) ? bktCnt[t] : 0;
  s[t] = v;
  __syncthreads();
  for (int off = 1; off < 1024; off <<= 1) {
    int a = (t >= off) ? s[t - off] : 0;
    __syncthreads();
    s[t] += a;
    __syncthreads();
  }
  if (t < NBKT) bktPtr[t] = s[t] - v;
}

// ---- pass B: place records bucket-grouped (LDS cursors only) ----
__global__ __launch_bounds__(256) void k_scat(const int* __restrict__ src,
                                              const int* __restrict__ dst,
                                              const float* __restrict__ ew,
                                              const int* __restrict__ blkOff,
                                              const int* __restrict__ bktPtr,
                                              uint2* __restrict__ recs) {
  __shared__ int cur[NBKT];
  int t = threadIdx.x, b = blockIdx.x;
  for (int i = t; i < NBKT; i += 256)
    cur[i] = bktPtr[i] + blkOff[(size_t)b * NBKT + i];
  __syncthreads();
  int base = b * EPB;
  #pragma unroll
  for (int k = 0; k < EPB / 256; ++k) {
    int e = base + t + k * 256;
    int d = dst[e];
    int p = atomicAdd(&cur[d >> 8], 1);
    recs[p] = make_uint2(((unsigned)src[e] << 8) | (unsigned)(d & 255),
                         __float_as_uint(ew[e]));
  }
}

// ---- degree from bucket records -> dinv ----
__global__ __launch_bounds__(256) void k_deg2(const int* __restrict__ bktPtr,
                                              const int* __restrict__ bktCnt,
                                              const uint2* __restrict__ recs,
                                              float* __restrict__ dinv) {
  __shared__ float dg[256];
  int t = threadIdx.x, k = blockIdx.x;
  dg[t] = 0.f;
  __syncthreads();
  int beg = bktPtr[k], end = beg + bktCnt[k];
  for (int i = beg + t; i < end; i += 256) {
    uint2 r = recs[i];
    atomicAdd(&dg[r.x & 255], __uint_as_float(r.y));
  }
  __syncthreads();
  dinv[k * 256 + t] = rsqrtf(dg[t] + 1.0f);
}

// ---- pass C: in-bucket sort by node -> recs2 (f = dinv[s]*w premult) + rowptr ----
__global__ __launch_bounds__(256) void k_sort2(
    const int* __restrict__ bktPtr, const int* __restrict__ bktCnt,
    const uint2* __restrict__ recs, const float* __restrict__ dinv,
    uint2* __restrict__ recs2, int* __restrict__ rowptr) {
  __shared__ int sc[256];
  __shared__ int cur[256];
  int t = threadIdx.x, k = blockIdx.x;
  sc[t] = 0;
  __syncthreads();
  int beg = bktPtr[k], cnt = bktCnt[k];
  for (int i = t; i < cnt; i += 256)
    atomicAdd(&sc[recs[beg + i].x & 255], 1);
  __syncthreads();
  int v = sc[t];
  __syncthreads();
  sc[t] = v;
  __syncthreads();
  for (int off = 1; off < 256; off <<= 1) {
    int a = (t >= off) ? sc[t - off] : 0;
    __syncthreads();
    sc[t] += a;
    __syncthreads();
  }
  int excl = beg + sc[t] - v;
  cur[t] = excl;
  rowptr[k * 256 + t] = excl;
  if (k == NBKT - 1 && t == 0) rowptr[NN] = NEdg;
  __syncthreads();
  for (int i = t; i < cnt; i += 256) {
    uint2 r = recs[beg + i];
    int p = atomicAdd(&cur[r.x & 255], 1);
    int s = (int)(r.x >> 8);
    recs2[p] = make_uint2(r.x, __float_as_uint(dinv[s] * __uint_as_float(r.y)));
  }
}

// ---- expand: x[n][0:32] fp16 ----
__global__ void k_expand(const float* __restrict__ ge, const float* __restrict__ Wexp,
                         const float* __restrict__ bexp, __half* __restrict__ xh) {
  int tid = blockIdx.x * 256 + threadIdx.x;
  if (tid >= NN * 8) return;
  int n = tid >> 3, q = tid & 7;
  int g = n / NV, v = n - g * NV;
  int col = v * H0 + q * 4;
  float4 acc = *(const float4*)(bexp + col);
  const float* gp = ge + g * EMB;
  #pragma unroll
  for (int k = 0; k < EMB; ++k) {
    float gk = gp[k];
    float4 w = *(const float4*)(Wexp + (size_t)k * (NV * H0) + col);
    acc.x += gk * w.x; acc.y += gk * w.y; acc.z += gk * w.z; acc.w += gk * w.w;
  }
  h4 o;
  o.a = __floats2half2_rn(acc.x, acc.y);
  o.b = __floats2half2_rn(acc.z, acc.w);
  *(h4*)(xh + (size_t)n * H0 + q * 4) = o;
}

// accumulate one 16B x-chunk (8 fp16 feats) into a[8]
__device__ __forceinline__ void acc_chunk(float4 tmp, float fj, float* a) {
  const __half2* hp = (const __half2*)&tmp;
  #pragma unroll
  for (int u = 0; u < 4; ++u) {
    float2 xy = __half22float2(hp[u]);
    a[2 * u]     += fj * xy.x;
    a[2 * u + 1] += fj * xy.y;
  }
}

// ---- pure gather: th[n][0:32] = fp16( dinv[n] * (dinv[n]*x[n] + sum f*x[s]) )
// wave = 16 nodes x 4 lanes (lane owns row-quarter q). Zero LDS, zero reduce.
__global__ __launch_bounds__(256) void k_agg(
    const int* __restrict__ rowptr, const uint2* __restrict__ recs,
    const float* __restrict__ dinv, const __half* __restrict__ xh,
    _Float16* __restrict__ th) {
  int t = threadIdx.x;
  int w = t >> 6, lane = t & 63;
  int grp = lane >> 2, q = lane & 3;
  int nbase = blockIdx.x * 64 + w * 16;

  int rp   = (lane < 17) ? rowptr[nbase + lane] : 0;
  float dv = (lane < 16) ? dinv[nbase + lane] : 0.f;
  int beg = __shfl(rp, grp);
  int cnt = __shfl(rp, grp + 1) - beg;
  float dd = __shfl(dv, grp);
  int n = nbase + grp;
  int tot = cnt + 1;                    // idx 0 = self loop

  float a[8];
  #pragma unroll
  for (int r = 0; r < 8; ++r) a[r] = 0.f;

  // round-0 rec (idx = q): q==0 -> self
  int rs = n; float rf = dd;
  if (q > 0) {
    if (q < tot) {
      uint2 rr = recs[beg + q - 1];
      rs = (int)(rr.x >> 8);
      rf = __uint_as_float(rr.y);
    } else rf = 0.f;
  }

  int rounds = (tot + 3) >> 2;
  for (int r = 0; r < rounds; ++r) {
    int rs_n = 0; float rf_n = 0.f;
    int idx_n = (r + 1) * 4 + q;
    if (idx_n < tot) {
      uint2 rr = recs[beg + idx_n - 1];
      rs_n = (int)(rr.x >> 8);
      rf_n = __uint_as_float(rr.y);
    }
    int base = r * 4;
    int nv = tot - base; nv = nv < 4 ? nv : 4;
    int ss[4]; float ff[4];
    #pragma unroll
    for (int k = 0; k < 4; ++k) {
      ss[k] = __shfl(rs, grp * 4 + k);
      ff[k] = __shfl(rf, grp * 4 + k);
    }
    float4 xv[4];
    #pragma unroll
    for (int k = 0; k < 4; ++k)
      if (k < nv) xv[k] = *((const float4*)(xh + (size_t)ss[k] * H0) + q);
    #pragma unroll
    for (int k = 0; k < 4; ++k)
      if (k < nv) acc_chunk(xv[k], ff[k], a);
    rs = rs_n; rf = rf_n;
  }

  half8_t o;
  #pragma unroll
  for (int r = 0; r < 8; ++r) o[r] = (_Float16)(dd * a[r]);
  *(half8_t*)(th + (size_t)n * H0 + q * 8) = o;
}

// ---- transform via MFMA: Y^T = W1^T @ T^T ; Z = relu(BN(Y)) @ W2 -> z[N,4] ----
// Per wave-iter: 16 nodes. A = W1^T tile (LDS, fp16), B = t-vectors (fp16).
// k-permutation applied identically to A and B => result invariant to HW k-order.
// C/D layout (HW-verified m89): col = lane&15, row = (lane>>4)*4 + reg.
__global__ __launch_bounds__(256) void k_tmfma(
    const _Float16* __restrict__ th,
    const float* __restrict__ W1, const float* __restrict__ b1,
    const float* __restrict__ W2,
    const float* __restrict__ gamma, const float* __restrict__ beta,
    const float* __restrict__ mean, const float* __restrict__ var,
    float* __restrict__ z) {
  __shared__ half8_t W1p[4][64];
  __shared__ float scale_s[H1], shift_s[H1];
  __shared__ float4 W2s4[H1];
  int t = threadIdx.x;
  {
    int c = t >> 6, l = t & 63;
    int col = c * 16 + (l & 15);
    int kb = (l >> 4) * 4;
    half8_t wv;
    #pragma unroll
    for (int f = 0; f < 8; ++f) {
      int k = ((f >> 2) * 16) + kb + (f & 3);
      wv[f] = (_Float16)W1[k * H1 + col];
    }
    W1p[c][l] = wv;
  }
  if (t < H1) {
    float sc = gamma[t] * rsqrtf(var[t] + BN_EPS);
    scale_s[t] = sc;
    shift_s[t] = beta[t] + (b1[t] - mean[t]) * sc;
    W2s4[t] = make_float4(W2[t * 3], W2[t * 3 + 1], W2[t * 3 + 2], 0.f);
  }
  __syncthreads();
  int w = t >> 6, lane = t & 63;
  int colL = lane & 15, kb = (lane >> 4) * 4;
  int nb0 = blockIdx.x * 256 + w * 64;
  #pragma unroll
  for (int it = 0; it < 4; ++it) {
    int n = nb0 + it * 16 + colL;
    const _Float16* tp = th + (size_t)n * H0 + kb;
    half4_t lo = *(const half4_t*)(tp);
    half4_t hi = *(const half4_t*)(tp + 16);
    half8_t b = {lo[0], lo[1], lo[2], lo[3], hi[0], hi[1], hi[2], hi[3]};
    float p0 = 0.f, p1 = 0.f, p2 = 0.f;
    #pragma unroll
    for (int c = 0; c < 4; ++c) {
      floatx4 acc = {0.f, 0.f, 0.f, 0.f};
      acc = __builtin_amdgcn_mfma_f32_16x16x32_f16(W1p[c][lane], b, acc, 0, 0, 0);
      #pragma unroll
      for (int reg = 0; reg < 4; ++reg) {
        int j = c * 16 + kb + reg;          // row = (lane>>4)*4 + reg
        float y = fmaxf(acc[reg] * scale_s[j] + shift_s[j], 0.f);
        float4 w2 = W2s4[j];
        p0 += y * w2.x; p1 += y * w2.y; p2 += y * w2.z;
      }
    }
    p0 += __shfl_xor(p0, 16); p1 += __shfl_xor(p1, 16); p2 += __shfl_xor(p2, 16);
    p0 += __shfl_xor(p0, 32); p1 += __shfl_xor(p1, 32); p2 += __shfl_xor(p2, 32);
    if (lane < 16)
      *(float4*)(z + (size_t)n * 4) = make_float4(p0, p1, p2, 0.f);
  }
}

// ---- layer 2: wave = 4 nodes x 16 lanes, premultiplied f ----
__global__ __launch_bounds__(256) void k_g2(
    const int* __restrict__ rowptr, const uint2* __restrict__ recs,
    const float* __restrict__ dinv, const float* __restrict__ z,
    const float* __restrict__ b2, float* __restrict__ out) {
  int t = threadIdx.x;
  int w = t >> 6, lane = t & 63;
  int si = lane >> 4, j = lane & 15;
  int n = blockIdx.x * 16 + w * 4 + si;
  int beg = rowptr[n];
  int tot = rowptr[n + 1] - beg + 1;          // + self at idx 0
  int s0 = n, s1 = n; float f0 = 0.f, f1 = 0.f, dd = 0.f;
  if (j == 0) {
    dd = dinv[n];
    f0 = dd;
  } else if (j < tot) {
    uint2 r = recs[beg + j - 1];
    s0 = (int)(r.x >> 8); f0 = __uint_as_float(r.y);
  }
  if (j + 16 < tot) {
    uint2 r = recs[beg + j + 15];
    s1 = (int)(r.x >> 8); f1 = __uint_as_float(r.y);
  }
  float4 z0 = *(const float4*)(z + (size_t)s0 * 4);
  float4 z1 = *(const float4*)(z + (size_t)s1 * 4);
  float a0 = f0 * z0.x + f1 * z1.x;
  float a1 = f0 * z0.y + f1 * z1.y;
  float a2 = f0 * z0.z + f1 * z1.z;
  if (tot > 32) {
    for (int idx = 32 + j; idx < tot; idx += 16) {
      uint2 r = recs[beg + idx - 1];
      int s = (int)(r.x >> 8);
      float f = __uint_as_float(r.y);
      const float4 zv = *(const float4*)(z + (size_t)s * 4);
      a0 += f * zv.x; a1 += f * zv.y; a2 += f * zv.z;
    }
  }
  a0 += __shfl_xor(a0, 1); a1 += __shfl_xor(a1, 1); a2 += __shfl_xor(a2, 1);
  a0 += __shfl_xor(a0, 2); a1 += __shfl_xor(a1, 2); a2 += __shfl_xor(a2, 2);
  a0 += __shfl_xor(a0, 4); a1 += __shfl_xor(a1, 4); a2 += __shfl_xor(a2, 4);
  a0 += __shfl_xor(a0, 8); a1 += __shfl_xor(a1, 8); a2 += __shfl_xor(a2, 8);
  if (j == 0) {
    float* op = out + (size_t)n * 3;
    op[0] = b2[0] + dd * a0;
    op[1] = b2[1] + dd * a1;
    op[2] = b2[2] + dd * a2;
  }
}

extern "C" void kernel_launch(void* const* d_in, const int* in_sizes, int n_in,
                              void* d_out, int out_size, void* d_ws, size_t ws_size,
                              hipStream_t stream) {
  const float* ge   = (const float*)d_in[0];
  const int*   ei   = (const int*)d_in[1];
  const float* ew   = (const float*)d_in[2];
  const float* Wexp = (const float*)d_in[3];
  const float* bexp = (const float*)d_in[4];
  const float* W1   = (const float*)d_in[5];
  const float* b1   = (const float*)d_in[6];
  const float* W2   = (const float*)d_in[7];
  const float* b2   = (const float*)d_in[8];
  const float* gam  = (const float*)d_in[9];
  const float* bet  = (const float*)d_in[10];
  const float* mu   = (const float*)d_in[11];
  const float* var  = (const float*)d_in[12];
  const int* src = ei;
  const int* dst = ei + NEdg;
  float* out = (float*)d_out;

  // workspace (everything fully overwritten before read -> no memset)
  uint2*    recs   = (uint2*)d_ws;                       // NEdg * 8B
  uint2*    recs2  = recs + NEdg;                        // NEdg * 8B
  float*    dinv   = (float*)(recs2 + NEdg);             // NN
  __half*   xh     = (__half*)(dinv + NN);               // NN*32 fp16
  _Float16* th     = (_Float16*)(xh + (size_t)NN * H0);  // NN*32 fp16
  float*    z      = (float*)(th + (size_t)NN * H0);     // NN*4 (padded)
  int*      rowptr = (int*)(z + (size_t)NN * 4);         // NN+1
  int*      blkOff = rowptr + NN + 1;                    // NBKT*NBKT
  int*      bktCnt = blkOff + (size_t)NBKT * NBKT;       // NBKT
  int*      bktPtr = bktCnt + NBKT;                      // NBKT

  k_hist   <<<NBKT, 256, 0, stream>>>(dst, blkOff);
  k_colscan<<<NBKT, 256, 0, stream>>>(blkOff, bktCnt);
  k_scanB  <<<1, 1024, 0, stream>>>(bktCnt, bktPtr);
  k_scat   <<<NBKT, 256, 0, stream>>>(src, dst, ew, blkOff, bktPtr, recs);
  k_deg2   <<<NBKT, 256, 0, stream>>>(bktPtr, bktCnt, recs, dinv);
  k_sort2  <<<NBKT, 256, 0, stream>>>(bktPtr, bktCnt, recs, dinv, recs2, rowptr);
  k_expand <<<NN * 8 / 256, 256, 0, stream>>>(ge, Wexp, bexp, xh);
  k_agg    <<<NN / 64, 256, 0, stream>>>(rowptr, recs2, dinv, xh, th);
  k_tmfma  <<<NN / 256, 256, 0, stream>>>(th, W1, b1, W2, gam, bet, mu, var, z);
  k_g2     <<<NN / 16, 256, 0, stream>>>(rowptr, recs2, dinv, z, b2, out);
}